// Round 3
// baseline (117.428 us; speedup 1.0000x reference)
//
#include <hip/hip_runtime.h>

// Problem constants (fixed by the reference: N=8192, F=256).
#define NN 8192
#define FF 256

// Clang-native vector type — required for __builtin_nontemporal_load/store
// (HIP's float4 is a class type the builtin rejects).
typedef float floatx4 __attribute__((ext_vector_type(4)));

// Kernel 1: per-row dual dot product.
// One 64-lane wave per row; F=256 = 64 lanes x float4.
// left[i] = dot(x[i], W[0:F]) + b ; right[i] = dot(x[i], W[F:2F])
__global__ void row_scores_kernel(const float* __restrict__ x,
                                  const float* __restrict__ W,
                                  const float* __restrict__ b,
                                  float* __restrict__ left,
                                  float* __restrict__ right) {
    const int row  = (int)((blockIdx.x * blockDim.x + threadIdx.x) >> 6);
    const int lane = (int)(threadIdx.x & 63);
    if (row >= NN) return;

    const floatx4 xv = reinterpret_cast<const floatx4*>(x + (size_t)row * FF)[lane];
    const floatx4 wl = reinterpret_cast<const floatx4*>(W)[lane];
    const floatx4 wr = reinterpret_cast<const floatx4*>(W + FF)[lane];

    float l = xv.x * wl.x + xv.y * wl.y + xv.z * wl.z + xv.w * wl.w;
    float r = xv.x * wr.x + xv.y * wr.y + xv.z * wr.z + xv.w * wr.w;

    #pragma unroll
    for (int off = 32; off; off >>= 1) {
        l += __shfl_down(l, off, 64);
        r += __shfl_down(r, off, 64);
    }
    if (lane == 0) {
        left[row]  = l + b[0];
        right[row] = r;
    }
}

// Kernel 2: out[i,j] = adj[i,j] * sigmoid(left[i] + right[j])
// Fixed geometry: 2048 blocks x 256 threads = 524288 threads; each thread
// owns exactly 32 float4s, processed as 8 iterations x 4 ILP-batched chunks.
// adj/out are streamed nontemporally (read-once / write-once); left/right
// stay in L1/L2 (32 KB each).
#define K2_THREADS (2048u * 256u)   // 524288
#define ILP 4

__device__ __forceinline__ float sigmoid_fast(float s) {
    // 1 / (1 + exp(-s)); exp via v_exp_f32, rcp via v_rcp_f32 (approx, ~1ulp)
    return __builtin_amdgcn_rcpf(1.0f + __expf(-s));
}

__global__ __launch_bounds__(256) void att_kernel(const float* __restrict__ adj,
                                                  const float* __restrict__ left,
                                                  const float* __restrict__ right,
                                                  float* __restrict__ out) {
    const unsigned tid = blockIdx.x * 256u + threadIdx.x;
    const floatx4* __restrict__ adj4   = reinterpret_cast<const floatx4*>(adj);
    const floatx4* __restrict__ right4 = reinterpret_cast<const floatx4*>(right);
    floatx4* __restrict__ out4         = reinterpret_cast<floatx4*>(out);

    #pragma unroll
    for (int it = 0; it < 8; ++it) {
        unsigned idx[ILP];
        floatx4 a[ILP], r[ILP];
        float   li[ILP];

        // Batch all loads first: 4 independent streaming loads in flight.
        #pragma unroll
        for (int k = 0; k < ILP; ++k) {
            idx[k] = tid + (unsigned)(it * ILP + k) * K2_THREADS;
            a[k]   = __builtin_nontemporal_load(&adj4[idx[k]]);
        }
        #pragma unroll
        for (int k = 0; k < ILP; ++k) {
            const unsigned i  = idx[k] >> 11;     // row (NN/4 = 2048 float4/row)
            const unsigned j4 = idx[k] & 2047u;   // col quad
            li[k] = left[i];                      // wave-uniform -> L1 broadcast
            r[k]  = right4[j4];                   // 32 KB table -> cache resident
        }

        // Compute + store.
        #pragma unroll
        for (int k = 0; k < ILP; ++k) {
            floatx4 o;
            o.x = a[k].x * sigmoid_fast(li[k] + r[k].x);
            o.y = a[k].y * sigmoid_fast(li[k] + r[k].y);
            o.z = a[k].z * sigmoid_fast(li[k] + r[k].z);
            o.w = a[k].w * sigmoid_fast(li[k] + r[k].w);
            __builtin_nontemporal_store(o, &out4[idx[k]]);
        }
    }
}

extern "C" void kernel_launch(void* const* d_in, const int* in_sizes, int n_in,
                              void* d_out, int out_size, void* d_ws, size_t ws_size,
                              hipStream_t stream) {
    const float* x   = (const float*)d_in[0];   // [N, F]
    const float* adj = (const float*)d_in[1];   // [N, N]
    const float* W   = (const float*)d_in[2];   // [2F, 1]
    const float* b   = (const float*)d_in[3];   // [1]
    float* out = (float*)d_out;                 // [N, N]

    float* left  = (float*)d_ws;                // N floats
    float* right = left + NN;                   // N floats

    // Kernel 1: 8192 waves = 524288 threads -> 2048 blocks of 256.
    row_scores_kernel<<<dim3((NN * 64) / 256), dim3(256), 0, stream>>>(x, W, b, left, right);

    // Kernel 2: 2048 blocks x 256 threads, 32 float4s/thread (8 iters x 4 ILP).
    att_kernel<<<dim3(2048), dim3(256), 0, stream>>>(adj, left, right, out);
}

// Round 4
// 112.244 us; speedup vs baseline: 1.0462x; 1.0462x over previous
//
#include <hip/hip_runtime.h>

// Problem constants (fixed by the reference: N=8192, F=256).
#define NN 8192
#define FF 256

typedef float floatx4 __attribute__((ext_vector_type(4)));

// Kernel 1: per-row dual dot product.
// One 64-lane wave per row; F=256 = 64 lanes x float4.
// left[i] = dot(x[i], W[0:F]) + b ; right[i] = dot(x[i], W[F:2F])
__global__ void row_scores_kernel(const float* __restrict__ x,
                                  const float* __restrict__ W,
                                  const float* __restrict__ b,
                                  float* __restrict__ left,
                                  float* __restrict__ right) {
    const int row  = (int)((blockIdx.x * blockDim.x + threadIdx.x) >> 6);
    const int lane = (int)(threadIdx.x & 63);
    if (row >= NN) return;

    const floatx4 xv = reinterpret_cast<const floatx4*>(x + (size_t)row * FF)[lane];
    const floatx4 wl = reinterpret_cast<const floatx4*>(W)[lane];
    const floatx4 wr = reinterpret_cast<const floatx4*>(W + FF)[lane];

    float l = xv.x * wl.x + xv.y * wl.y + xv.z * wl.z + xv.w * wl.w;
    float r = xv.x * wr.x + xv.y * wr.y + xv.z * wr.z + xv.w * wr.w;

    #pragma unroll
    for (int off = 32; off; off >>= 1) {
        l += __shfl_down(l, off, 64);
        r += __shfl_down(r, off, 64);
    }
    if (lane == 0) {
        left[row]  = l + b[0];
        right[row] = r;
    }
}

__device__ __forceinline__ float sigmoid_fast(float s) {
    // 1 / (1 + exp(-s)); exp via v_exp_f32, rcp via v_rcp_f32 (approx, ~1ulp)
    return __builtin_amdgcn_rcpf(1.0f + __expf(-s));
}

// Kernel 2: out[i,j] = adj[i,j] * sigmoid(left[i] + right[j])
// Block-per-row-group mapping: block b owns rows [4b, 4b+4).
//  - left[4b..4b+3] are block-uniform -> scalar (SGPR) loads, no per-lane VMEM.
//  - each thread's 8 right-quads hoisted into registers once, reused x4 rows.
//  - inner loop: exactly 1 coalesced adj load + compute + 1 coalesced store.
#define ROWS_PER_BLOCK 4
#define Q_PER_ROW (NN / 4 / 256)   // 8 float4-quads per thread per row

__global__ __launch_bounds__(256) void att_kernel(const float* __restrict__ adj,
                                                  const float* __restrict__ left,
                                                  const float* __restrict__ right,
                                                  float* __restrict__ out) {
    const unsigned t  = threadIdx.x;
    const unsigned r0 = blockIdx.x * ROWS_PER_BLOCK;

    const floatx4* __restrict__ adj4   = reinterpret_cast<const floatx4*>(adj);
    const floatx4* __restrict__ right4 = reinterpret_cast<const floatx4*>(right);
    floatx4* __restrict__ out4         = reinterpret_cast<floatx4*>(out);

    // Hoist this thread's right-quads into registers (static indexing -> VGPRs).
    floatx4 rq[Q_PER_ROW];
    #pragma unroll
    for (int q = 0; q < Q_PER_ROW; ++q)
        rq[q] = right4[t + (unsigned)q * 256u];

    // Block-uniform left scores (compiler emits scalar loads).
    float lrow[ROWS_PER_BLOCK];
    #pragma unroll
    for (int k = 0; k < ROWS_PER_BLOCK; ++k)
        lrow[k] = left[r0 + k];

    #pragma unroll
    for (int k = 0; k < ROWS_PER_BLOCK; ++k) {
        const unsigned rowbase = (r0 + k) * (NN / 4);
        const float li = lrow[k];
        #pragma unroll
        for (int q = 0; q < Q_PER_ROW; ++q) {
            const unsigned idx = rowbase + t + (unsigned)q * 256u;
            const floatx4 a = adj4[idx];
            floatx4 o;
            o.x = a.x * sigmoid_fast(li + rq[q].x);
            o.y = a.y * sigmoid_fast(li + rq[q].y);
            o.z = a.z * sigmoid_fast(li + rq[q].z);
            o.w = a.w * sigmoid_fast(li + rq[q].w);
            out4[idx] = o;
        }
    }
}

extern "C" void kernel_launch(void* const* d_in, const int* in_sizes, int n_in,
                              void* d_out, int out_size, void* d_ws, size_t ws_size,
                              hipStream_t stream) {
    const float* x   = (const float*)d_in[0];   // [N, F]
    const float* adj = (const float*)d_in[1];   // [N, N]
    const float* W   = (const float*)d_in[2];   // [2F, 1]
    const float* b   = (const float*)d_in[3];   // [1]
    float* out = (float*)d_out;                 // [N, N]

    float* left  = (float*)d_ws;                // N floats
    float* right = left + NN;                   // N floats

    // Kernel 1: 8192 waves = 524288 threads -> 2048 blocks of 256.
    row_scores_kernel<<<dim3((NN * 64) / 256), dim3(256), 0, stream>>>(x, W, b, left, right);

    // Kernel 2: 2048 blocks x 256 threads; block b owns rows [4b, 4b+4).
    att_kernel<<<dim3(NN / ROWS_PER_BLOCK), dim3(256), 0, stream>>>(adj, left, right, out);
}

// Round 5
// 100.479 us; speedup vs baseline: 1.1687x; 1.1171x over previous
//
#include <hip/hip_runtime.h>

// Problem constants (fixed by the reference: N=8192, F=256).
#define NN 8192
#define FF 256

typedef float floatx4 __attribute__((ext_vector_type(4)));

// Kernel 1: per-row dual dot product.
// One 64-lane wave per row; F=256 = 64 lanes x float4.
__global__ void row_scores_kernel(const float* __restrict__ x,
                                  const float* __restrict__ W,
                                  const float* __restrict__ b,
                                  float* __restrict__ left,
                                  float* __restrict__ right) {
    const int row  = (int)((blockIdx.x * blockDim.x + threadIdx.x) >> 6);
    const int lane = (int)(threadIdx.x & 63);
    if (row >= NN) return;

    const floatx4 xv = reinterpret_cast<const floatx4*>(x + (size_t)row * FF)[lane];
    const floatx4 wl = reinterpret_cast<const floatx4*>(W)[lane];
    const floatx4 wr = reinterpret_cast<const floatx4*>(W + FF)[lane];

    float l = xv.x * wl.x + xv.y * wl.y + xv.z * wl.z + xv.w * wl.w;
    float r = xv.x * wr.x + xv.y * wr.y + xv.z * wr.z + xv.w * wr.w;

    #pragma unroll
    for (int off = 32; off; off >>= 1) {
        l += __shfl_down(l, off, 64);
        r += __shfl_down(r, off, 64);
    }
    if (lane == 0) {
        left[row]  = l + b[0];
        right[row] = r;
    }
}

__device__ __forceinline__ float sigmoid_fast(float s) {
    return __builtin_amdgcn_rcpf(1.0f + __expf(-s));
}

// Kernel 2: out[i,j] = adj[i,j] * sigmoid(left[i] + right[j])
// Block b owns rows [4b, 4b+4). left -> SGPR scalar loads; right quads hoisted
// to 32 VGPRs and reused across the 4 rows. Row loop is NOT unrolled
// (#pragma unroll 1) to bound VGPRs/in-flight loads -> keep occupancy high;
// TLP (32 waves/CU) supplies the memory parallelism. NT store: out is
// write-once, never re-read -> don't allocate L2 lines for it.
#define ROWS_PER_BLOCK 4
#define Q_PER_ROW (NN / 4 / 256)   // 8 float4-quads per thread per row

__global__ __launch_bounds__(256) void att_kernel(const float* __restrict__ adj,
                                                  const float* __restrict__ left,
                                                  const float* __restrict__ right,
                                                  float* __restrict__ out) {
    const unsigned t  = threadIdx.x;
    const unsigned r0 = blockIdx.x * ROWS_PER_BLOCK;

    const floatx4* __restrict__ adj4   = reinterpret_cast<const floatx4*>(adj);
    const floatx4* __restrict__ right4 = reinterpret_cast<const floatx4*>(right);
    floatx4* __restrict__ out4         = reinterpret_cast<floatx4*>(out);

    floatx4 rq[Q_PER_ROW];
    #pragma unroll
    for (int q = 0; q < Q_PER_ROW; ++q)
        rq[q] = right4[t + (unsigned)q * 256u];

    float lrow[ROWS_PER_BLOCK];
    #pragma unroll
    for (int k = 0; k < ROWS_PER_BLOCK; ++k)
        lrow[k] = left[r0 + k];

    #pragma unroll 1
    for (int k = 0; k < ROWS_PER_BLOCK; ++k) {
        const unsigned rowbase = (r0 + k) * (NN / 4);
        const float li = lrow[k];
        #pragma unroll
        for (int q = 0; q < Q_PER_ROW; ++q) {
            const unsigned idx = rowbase + t + (unsigned)q * 256u;
            const floatx4 a = adj4[idx];
            floatx4 o;
            o.x = a.x * sigmoid_fast(li + rq[q].x);
            o.y = a.y * sigmoid_fast(li + rq[q].y);
            o.z = a.z * sigmoid_fast(li + rq[q].z);
            o.w = a.w * sigmoid_fast(li + rq[q].w);
            __builtin_nontemporal_store(o, &out4[idx]);
        }
    }
}

extern "C" void kernel_launch(void* const* d_in, const int* in_sizes, int n_in,
                              void* d_out, int out_size, void* d_ws, size_t ws_size,
                              hipStream_t stream) {
    const float* x   = (const float*)d_in[0];   // [N, F]
    const float* adj = (const float*)d_in[1];   // [N, N]
    const float* W   = (const float*)d_in[2];   // [2F, 1]
    const float* b   = (const float*)d_in[3];   // [1]
    float* out = (float*)d_out;                 // [N, N]

    float* left  = (float*)d_ws;                // N floats
    float* right = left + NN;                   // N floats

    row_scores_kernel<<<dim3((NN * 64) / 256), dim3(256), 0, stream>>>(x, W, b, left, right);
    att_kernel<<<dim3(NN / ROWS_PER_BLOCK), dim3(256), 0, stream>>>(adj, left, right, out);
}